// Round 1
// 201.252 us; speedup vs baseline: 1.0223x; 1.0223x over previous
//
#include <hip/hip_runtime.h>
#include <stdint.h>
#include <math.h>

#define E_DIM 1024
#define W_DIM 1024
#define EW 1048576L   // 1024*1024

typedef _Float16 h16;
typedef __attribute__((ext_vector_type(8))) _Float16 h8;
typedef __attribute__((ext_vector_type(4))) float f4;

__device__ __forceinline__ void async_copy16(h16* lds, const h16* g) {
    __builtin_amdgcn_global_load_lds(
        (const __attribute__((address_space(1))) void*)g,
        (__attribute__((address_space(3))) void*)lds, 16, 0, 0);
}

// ---------------------------------------------------------------------------
// prep: z<12 -> transpose-convert x [12][E][W] fp32 -> [12][W][E] fp16;
//       z>=12 -> convert weight (z-12) fp32 -> fp16 into wh[LK|LQ|LV|M].
// ---------------------------------------------------------------------------
__global__ __launch_bounds__(256) void prep(
    const float* __restrict__ x, const float* __restrict__ LK,
    const float* __restrict__ LQ, const float* __restrict__ LV,
    const float* __restrict__ Mw, h16* __restrict__ xt, h16* __restrict__ wh)
{
    __shared__ float Ts[64][65];
    const int z = blockIdx.z;
    const int t = threadIdx.x;
    if (z < 12) {
        const float* src = x + (long)z * EW;   // [e][w]
        h16* dst = xt + (long)z * EW;          // [w][e]
        const int e0 = blockIdx.y * 64, w0 = blockIdx.x * 64;
        const int r = t >> 4, c4 = (t & 15) * 4;
        #pragma unroll
        for (int p = 0; p < 4; ++p) {
            float4 v = *reinterpret_cast<const float4*>(src + (long)(e0 + r + p * 16) * W_DIM + w0 + c4);
            Ts[c4 + 0][r + p * 16] = v.x;
            Ts[c4 + 1][r + p * 16] = v.y;
            Ts[c4 + 2][r + p * 16] = v.z;
            Ts[c4 + 3][r + p * 16] = v.w;
        }
        __syncthreads();
        #pragma unroll
        for (int p = 0; p < 4; ++p) {
            int wr = r + p * 16;
            union { h16 h[4]; uint2 u; } o;
            o.h[0] = (h16)Ts[wr][c4 + 0];
            o.h[1] = (h16)Ts[wr][c4 + 1];
            o.h[2] = (h16)Ts[wr][c4 + 2];
            o.h[3] = (h16)Ts[wr][c4 + 3];
            *reinterpret_cast<uint2*>(dst + (long)(w0 + wr) * E_DIM + e0 + c4) = o.u;
        }
    } else {
        const float* srcs[4] = {LK, LQ, LV, Mw};
        const float* s = srcs[z - 12];
        h16* o = wh + (long)(z - 12) * EW;
        long base = ((long)(blockIdx.y * 16 + blockIdx.x)) * 1024 + t;  // float4 idx
        #pragma unroll
        for (int k = 0; k < 4; ++k) {
            long i = base + k * 256;
            float4 v = reinterpret_cast<const float4*>(s)[i];
            union { h16 h[4]; uint2 u; } u;
            u.h[0] = (h16)v.x; u.h[1] = (h16)v.y; u.h[2] = (h16)v.z; u.h[3] = (h16)v.w;
            reinterpret_cast<uint2*>(o)[i] = u.u;
        }
    }
}

// ---------------------------------------------------------------------------
// Fused projection GEMMs (K, Q, V), z = proj*4 + batch. 128x128 tile,
// BK=64, m97-style single-buffer 2-barrier K-loop, XOR-swizzled granules.
// ---------------------------------------------------------------------------
__global__ __launch_bounds__(256) void gemm_proj3(
    const h16* __restrict__ xh, const h16* __restrict__ Wts,
    h16* __restrict__ KQV)
{
    __shared__ h16 As[128 * 64];
    __shared__ h16 Bs[128 * 64];

    const int t = threadIdx.x;
    const int wave = t >> 6, lane = t & 63;
    const int quad = lane >> 4, l16 = lane & 15;
    const int m0 = blockIdx.y * 128, n0 = blockIdx.x * 128;
    const int wm = (wave >> 1) * 64, wn = (wave & 1) * 64;

    const int proj = blockIdx.z >> 2, bz = blockIdx.z & 3;
    const h16 *A, *Bt; h16* C;
    if (proj == 0)      { A = xh + bz * EW;       Bt = Wts;          C = KQV + bz * EW; }
    else if (proj == 1) { A = xh + (4 + bz) * EW; Bt = Wts + EW;     C = KQV + (4 + bz) * EW; }
    else                { A = Wts + 2 * EW;       Bt = xh + (8 + bz) * EW; C = KQV + (8 + bz) * EW; }

    f4 acc[4][4] = {};

    for (int k0 = 0; k0 < 1024; k0 += 64) {
        __syncthreads();
        #pragma unroll
        for (int j = 0; j < 4; ++j) {
            int g = j * 256 + t, row = g >> 3, cg = (g & 7) ^ (row & 7);
            async_copy16(&As[g * 8], A  + (long)(m0 + row) * E_DIM + k0 + cg * 8);
            async_copy16(&Bs[g * 8], Bt + (long)(n0 + row) * E_DIM + k0 + cg * 8);
        }
        __syncthreads();

        h8 av[4][2], bv[4][2];
        #pragma unroll
        for (int i = 0; i < 4; ++i) {
            int ra = wm + i * 16 + l16, rb = wn + i * 16 + l16;
            #pragma unroll
            for (int c = 0; c < 2; ++c) {
                av[i][c] = *reinterpret_cast<const h8*>(&As[(ra * 8 + ((c * 4 + quad) ^ (l16 & 7))) * 8]);
                bv[i][c] = *reinterpret_cast<const h8*>(&Bs[(rb * 8 + ((c * 4 + quad) ^ (l16 & 7))) * 8]);
            }
        }
        #pragma unroll
        for (int c = 0; c < 2; ++c)
            #pragma unroll
            for (int mt = 0; mt < 4; ++mt)
                #pragma unroll
                for (int nt = 0; nt < 4; ++nt)
                    acc[mt][nt] = __builtin_amdgcn_mfma_f32_16x16x32_f16(av[mt][c], bv[nt][c], acc[mt][nt], 0, 0, 0);
    }

    #pragma unroll
    for (int mt = 0; mt < 4; ++mt)
        #pragma unroll
        for (int i = 0; i < 4; ++i) {
            int m = m0 + wm + mt * 16 + quad * 4 + i;
            #pragma unroll
            for (int nt = 0; nt < 4; ++nt)
                C[(long)m * W_DIM + n0 + wn + nt * 16 + l16] = (h16)acc[mt][nt][i];
        }
}

// ---------------------------------------------------------------------------
// Output GEMM, batch-fused: out = M[1024x1024] x Ao[4096x1024]^T (+bias).
// ---------------------------------------------------------------------------
__global__ __launch_bounds__(256) void gemm_out(
    const h16* __restrict__ A, const h16* __restrict__ Bt,
    float* __restrict__ C, const float* __restrict__ bias)
{
    __shared__ h16 As[64 * 64];
    __shared__ h16 Bs[128 * 64];

    const int t = threadIdx.x;
    const int wave = t >> 6, lane = t & 63;
    const int quad = lane >> 4, l16 = lane & 15;
    const int m0 = blockIdx.y * 64, n0 = blockIdx.x * 128;
    const int wm = (wave >> 1) * 32, wn = (wave & 1) * 64;

    f4 acc[2][4] = {};

    for (int k0 = 0; k0 < 1024; k0 += 64) {
        __syncthreads();
        #pragma unroll
        for (int j = 0; j < 2; ++j) {
            int g = j * 256 + t, row = g >> 3, cg = (g & 7) ^ (row & 7);
            async_copy16(&As[g * 8], A + (long)(m0 + row) * E_DIM + k0 + cg * 8);
        }
        #pragma unroll
        for (int j = 0; j < 4; ++j) {
            int g = j * 256 + t, row = g >> 3, cg = (g & 7) ^ (row & 7);
            async_copy16(&Bs[g * 8], Bt + (long)(n0 + row) * E_DIM + k0 + cg * 8);
        }
        __syncthreads();

        h8 av[2][2], bv[4][2];
        #pragma unroll
        for (int c = 0; c < 2; ++c) {
            #pragma unroll
            for (int mt = 0; mt < 2; ++mt) {
                int r = wm + mt * 16 + l16;
                av[mt][c] = *reinterpret_cast<const h8*>(&As[(r * 8 + ((c * 4 + quad) ^ (l16 & 7))) * 8]);
            }
            #pragma unroll
            for (int nt = 0; nt < 4; ++nt) {
                int r = wn + nt * 16 + l16;
                bv[nt][c] = *reinterpret_cast<const h8*>(&Bs[(r * 8 + ((c * 4 + quad) ^ (l16 & 7))) * 8]);
            }
        }
        #pragma unroll
        for (int c = 0; c < 2; ++c)
            #pragma unroll
            for (int mt = 0; mt < 2; ++mt)
                #pragma unroll
                for (int nt = 0; nt < 4; ++nt)
                    acc[mt][nt] = __builtin_amdgcn_mfma_f32_16x16x32_f16(av[mt][c], bv[nt][c], acc[mt][nt], 0, 0, 0);
    }

    #pragma unroll
    for (int mt = 0; mt < 2; ++mt)
        #pragma unroll
        for (int i = 0; i < 4; ++i) {
            int m = m0 + wm + mt * 16 + quad * 4 + i;
            float bv_ = bias ? bias[m] : 0.f;
            #pragma unroll
            for (int nt = 0; nt < 4; ++nt) {
                int n = n0 + wn + nt * 16 + l16;   // n = b*1024 + w
                C[(long)(n >> 10) * EW + (long)m * W_DIM + (n & 1023)] = acc[mt][nt][i] + bv_;
            }
        }
}

// ---------------------------------------------------------------------------
// MFMA flash attention (softmax over q), 128-wide k blocks:
//  - grid (8,64): block = (b,h) x 128 k-cols; wave owns 32 k-cols (2 groups)
//  - Q/V tiles DMA-staged, double-buffered, ONE barrier per 64-q step; each
//    staged tile + each LDS fragment read now feeds 2x the MFMAs
//  - complementary ktb pairing (id ^ cxor) flattens per-CU load when all 512
//    blocks are resident (id & id+256 sum to 18 iterations)
//  - exp2-domain softmax + defer-max (THR=8) + tree reductions
//  - per-wave P^T scratch [32][64], pitch-64 XOR-swizzled granules
// ---------------------------------------------------------------------------
__global__ __launch_bounds__(256) void attn_mfma(
    const h16* __restrict__ Kt, const h16* __restrict__ Qt,
    const h16* __restrict__ V, h16* __restrict__ AoT)
{
    __shared__ h16 Qs[2][64 * 64];   // [q][d] swizzled granules
    __shared__ h16 Vs[2][64 * 64];   // [d][q] swizzled granules
    __shared__ h16 Ps[4][32 * 64];   // per-wave P^T [k32][q64] swizzled granules

    const int t = threadIdx.x, wave = t >> 6, lane = t & 63;
    const int quad = lane >> 4, l16 = lane & 15;
    const int y = blockIdx.y;
    const int b = y >> 4, h = y & 15;
    const int cxor = (y & 7) ^ (((y >> 5) & 1) ? 7 : 0);
    const int ktb = (int)blockIdx.x ^ cxor;     // 0..7; id & id+256 complementary
    const int nit = 2 * ktb + 2;
    const int kwave = ktb * 128 + wave * 32;    // wave's first k column
    const int kc0 = kwave + l16, kc1 = kc0 + 16;

    const h16* Ktb_ = Kt + (long)b * EW + h * 64;
    const h16* Qtb  = Qt + (long)b * EW + h * 64;
    const h16* Vb   = V  + (long)b * EW + (long)(h * 64) * W_DIM;
    h16* Pw = &Ps[wave][0];

    // K in registers: group g, half c -> K^T[kc_g][c*32 + quad*8 + j]
    h8 kb00 = *reinterpret_cast<const h8*>(Ktb_ + (long)kc0 * E_DIM + quad * 8);
    h8 kb01 = *reinterpret_cast<const h8*>(Ktb_ + (long)kc0 * E_DIM + 32 + quad * 8);
    h8 kb10 = *reinterpret_cast<const h8*>(Ktb_ + (long)kc1 * E_DIM + quad * 8);
    h8 kb11 = *reinterpret_cast<const h8*>(Ktb_ + (long)kc1 * E_DIM + 32 + quad * 8);

    // stage tile 0 into buf 0
    #pragma unroll
    for (int j = 0; j < 2; ++j) {
        int g = j * 256 + t, row = g >> 3, cg = (g & 7) ^ (row & 7);
        async_copy16(&Qs[0][g * 8], Qtb + (long)row * E_DIM + cg * 8);
        async_copy16(&Vs[0][g * 8], Vb + (long)row * W_DIM + cg * 8);
    }

    const float L2E = 1.442695041f;
    float mr0 = -1e30f, mr1 = -1e30f, ls0 = 0.f, ls1 = 0.f;
    f4 O[4][2] = {};

    for (int it = 0; it < nit; ++it) {
        const int q0 = it * 64;
        __syncthreads();   // drains DMA for buf it&1; prev iter's readers done
        if (it + 1 < nit) {
            const int nb = (it + 1) & 1, q1 = q0 + 64;
            #pragma unroll
            for (int j = 0; j < 2; ++j) {
                int g = j * 256 + t, row = g >> 3, cg = (g & 7) ^ (row & 7);
                async_copy16(&Qs[nb][g * 8], Qtb + (long)(q1 + row) * E_DIM + cg * 8);
                async_copy16(&Vs[nb][g * 8], Vb + (long)row * W_DIM + q1 + cg * 8);
            }
        }
        if (q0 > kwave + 31) continue;   // wave fully masked on this q-tile

        const h16* qs = Qs[it & 1];
        const h16* vs = Vs[it & 1];

        // S^T[q][k] for both k-groups; Q fragments shared
        f4 S0[4], S1[4];
        __builtin_amdgcn_s_setprio(1);
        #pragma unroll
        for (int nt = 0; nt < 4; ++nt) {
            int row = nt * 16 + l16;
            h8 a0 = *reinterpret_cast<const h8*>(&qs[(row * 8 + (quad ^ (l16 & 7))) * 8]);
            h8 a1 = *reinterpret_cast<const h8*>(&qs[(row * 8 + ((4 + quad) ^ (l16 & 7))) * 8]);
            f4 s0 = {}, s1 = {};
            s0 = __builtin_amdgcn_mfma_f32_16x16x32_f16(a0, kb00, s0, 0, 0, 0);
            s1 = __builtin_amdgcn_mfma_f32_16x16x32_f16(a0, kb10, s1, 0, 0, 0);
            s0 = __builtin_amdgcn_mfma_f32_16x16x32_f16(a1, kb01, s0, 0, 0, 0);
            s1 = __builtin_amdgcn_mfma_f32_16x16x32_f16(a1, kb11, s1, 0, 0, 0);
            S0[nt] = s0; S1[nt] = s1;
        }
        __builtin_amdgcn_s_setprio(0);

        if (it >= 2 * ktb) {   // diagonal region: mask q > k
            #pragma unroll
            for (int nt = 0; nt < 4; ++nt)
                #pragma unroll
                for (int i = 0; i < 4; ++i) {
                    int q = q0 + nt * 16 + quad * 4 + i;
                    if (q > kc0) S0[nt][i] = -1e30f;
                    if (q > kc1) S1[nt][i] = -1e30f;
                }
        }

        // tile max per column (tree, both groups interleaved)
        float mx0 = -1e30f, mx1 = -1e30f;
        #pragma unroll
        for (int nt = 0; nt < 4; ++nt) {
            float t0 = fmaxf(fmaxf(S0[nt][0], S0[nt][1]), fmaxf(S0[nt][2], S0[nt][3]));
            float t1 = fmaxf(fmaxf(S1[nt][0], S1[nt][1]), fmaxf(S1[nt][2], S1[nt][3]));
            mx0 = fmaxf(mx0, t0); mx1 = fmaxf(mx1, t1);
        }
        mx0 = fmaxf(mx0, __shfl_xor(mx0, 16)); mx1 = fmaxf(mx1, __shfl_xor(mx1, 16));
        mx0 = fmaxf(mx0, __shfl_xor(mx0, 32)); mx1 = fmaxf(mx1, __shfl_xor(mx1, 32));

        // defer-max: only rescale when some column grew past THR=8
        if (__any((mx0 - mr0 > 8.f) || (mx1 - mr1 > 8.f))) {
            float nm0 = fmaxf(mr0, mx0), nm1 = fmaxf(mr1, mx1);
            float al0 = exp2f((mr0 - nm0) * L2E), al1 = exp2f((mr1 - nm1) * L2E);
            mr0 = nm0; mr1 = nm1;
            ls0 *= al0; ls1 *= al1;
            #pragma unroll
            for (int dt = 0; dt < 4; ++dt)
                #pragma unroll
                for (int i = 0; i < 4; ++i) { O[dt][0][i] *= al0; O[dt][1][i] *= al1; }
        }

        const float mc0 = mr0 * L2E, mc1 = mr1 * L2E;
        float tsa = 0.f, tsb = 0.f, tsc = 0.f, tsd = 0.f;
        #pragma unroll
        for (int nt = 0; nt < 4; ++nt)
            #pragma unroll
            for (int i = 0; i < 4; ++i) {
                float p0 = exp2f(fmaf(S0[nt][i], L2E, -mc0));
                float p1 = exp2f(fmaf(S1[nt][i], L2E, -mc1));
                S0[nt][i] = p0; S1[nt][i] = p1;
                if (i & 1) { tsb += p0; tsd += p1; } else { tsa += p0; tsc += p1; }
            }
        float ts0 = tsa + tsb, ts1 = tsc + tsd;
        ts0 += __shfl_xor(ts0, 16); ts1 += __shfl_xor(ts1, 16);
        ts0 += __shfl_xor(ts0, 32); ts1 += __shfl_xor(ts1, 32);
        ls0 += ts0; ls1 += ts1;

        // P^T -> per-wave LDS: rows l16 (g0) and 16+l16 (g1), swizzled granules
        #pragma unroll
        for (int nt = 0; nt < 4; ++nt) {
            int sg = ((nt * 2 + (quad >> 1)) ^ (l16 & 7)) * 8 + (quad & 1) * 4;
            union { h16 hh[4]; uint2 u2; } u0, u1;
            #pragma unroll
            for (int i = 0; i < 4; ++i) { u0.hh[i] = (h16)S0[nt][i]; u1.hh[i] = (h16)S1[nt][i]; }
            *reinterpret_cast<uint2*>(Pw + l16 * 64 + sg) = u0.u2;
            *reinterpret_cast<uint2*>(Pw + (16 + l16) * 64 + sg) = u1.u2;
        }
        asm volatile("" ::: "memory");   // DS in-order per wave; read after write

        // OUT^T[d][k] += V[d][q] * P[q][k]; V fragment shared across both groups
        __builtin_amdgcn_s_setprio(1);
        #pragma unroll
        for (int c = 0; c < 2; ++c) {
            int sg = ((c * 4 + quad) ^ (l16 & 7)) * 8;
            h8 p0 = *reinterpret_cast<const h8*>(Pw + l16 * 64 + sg);
            h8 p1 = *reinterpret_cast<const h8*>(Pw + (16 + l16) * 64 + sg);
            #pragma unroll
            for (int dt = 0; dt < 4; ++dt) {
                int r = dt * 16 + l16;
                h8 va = *reinterpret_cast<const h8*>(&vs[(r * 8 + ((c * 4 + quad) ^ (l16 & 7))) * 8]);
                O[dt][0] = __builtin_amdgcn_mfma_f32_16x16x32_f16(va, p0, O[dt][0], 0, 0, 0);
                O[dt][1] = __builtin_amdgcn_mfma_f32_16x16x32_f16(va, p1, O[dt][1], 0, 0, 0);
            }
        }
        __builtin_amdgcn_s_setprio(0);
    }

    // epilogue: O cols k, rows d -> transpose via Pw, store rows of AoT
    const float inv0 = 0.03125f / ls0, inv1 = 0.03125f / ls1;
    #pragma unroll
    for (int dt = 0; dt < 4; ++dt) {
        int sg = ((dt * 2 + (quad >> 1)) ^ (l16 & 7)) * 8 + (quad & 1) * 4;
        union { h16 hh[4]; uint2 u2; } u0, u1;
        #pragma unroll
        for (int i = 0; i < 4; ++i) {
            u0.hh[i] = (h16)(O[dt][0][i] * inv0);
            u1.hh[i] = (h16)(O[dt][1][i] * inv1);
        }
        *reinterpret_cast<uint2*>(Pw + l16 * 64 + sg) = u0.u2;
        *reinterpret_cast<uint2*>(Pw + (16 + l16) * 64 + sg) = u1.u2;
    }
    asm volatile("" ::: "memory");
    #pragma unroll
    for (int g = 0; g < 2; ++g)
        #pragma unroll
        for (int j = 0; j < 2; ++j) {
            int sg = ((quad * 2 + j) ^ (l16 & 7)) * 8;
            uint4 vv = *reinterpret_cast<const uint4*>(Pw + (g * 16 + l16) * 64 + sg);
            *reinterpret_cast<uint4*>(AoT + (long)b * EW
                                      + (long)(kwave + g * 16 + l16) * E_DIM
                                      + h * 64 + quad * 16 + j * 8) = vv;
        }
}

// ---------------------------------------------------------------------------
extern "C" void kernel_launch(void* const* d_in, const int* in_sizes, int n_in,
                              void* d_out, int out_size, void* d_ws, size_t ws_size,
                              hipStream_t stream)
{
    const float* x  = (const float*)d_in[0];  // [3][B][E][W]; x[0]->K, x[1]->Q, x[2]->V
    const float* LQ = (const float*)d_in[1];
    const float* LK = (const float*)d_in[2];
    const float* LV = (const float*)d_in[3];
    const float* Mw = (const float*)d_in[4];
    const float* bb = (const float*)d_in[5];
    float* out = (float*)d_out;
    h16* ws = (h16*)d_ws;

    h16* xh  = ws;                    // [12][W][E] transposed x
    h16* LKh = ws + 12 * EW;          // weights [LK|LQ|LV|M]
    h16* Mh  = ws + 15 * EW;
    h16* Kp  = ws + 16 * EW;          // [B][W][E] (K^T)
    h16* Qp  = ws + 20 * EW;          // [B][W][E] (Q^T)
    h16* Vp  = ws + 24 * EW;          // [B][E][W] (V)
    h16* Ao  = ws + 28 * EW;          // [B][W][E] (attn out^T) = [4096][1024]

    dim3 blk(256);
    prep<<<dim3(16, 16, 16), blk, 0, stream>>>(x, LK, LQ, LV, Mw, xh, LKh);
    gemm_proj3<<<dim3(8, 8, 12), blk, 0, stream>>>(xh, LKh, Kp);
    attn_mfma<<<dim3(8, 64), blk, 0, stream>>>(Kp, Qp, Vp, Ao);
    gemm_out<<<dim3(32, 16), blk, 0, stream>>>(Mh, Ao, out, bb);
}